// Round 1
// baseline (220.752 us; speedup 1.0000x reference)
//
#include <hip/hip_runtime.h>

// Spatial transformer: affine grid-sample, reflect padding, bilinear.
// x: (B=32, C=3, H=512, W=512) fp32; p: (B,4) fp32 = [tx, ty, theta, scale].
// out[b,c,row,col] = bilinear(x[b,c], reflect(ix), reflect(iy))

#define B_ 32
#define C_ 3
#define H_ 512
#define W_ 512

__device__ __forceinline__ float reflect_coord(float coord, int size) {
    float span = (float)size;
    float c = fabsf(coord + 0.5f);
    float flips = floorf(c / span);
    float extra = c - flips * span;
    float m = fmodf(flips, 2.0f);
    c = ((m == 0.0f) ? extra : (span - extra)) - 0.5f;
    return fminf(fmaxf(c, 0.0f), (float)(size - 1));
}

__global__ __launch_bounds__(256)
void st_kernel(const float* __restrict__ x, const float* __restrict__ p,
               float* __restrict__ out) {
    const int col = blockIdx.x * blockDim.x + threadIdx.x;
    const int row = blockIdx.y;
    const int b   = blockIdx.z;   // wave-uniform -> scalar param loads

    const float tx = p[b * 4 + 0];
    const float ty = p[b * 4 + 1];
    const float th = p[b * 4 + 2];
    const float ts = p[b * 4 + 3];
    const float cth = cosf(th), sth = sinf(th);
    const float a  =  ts * cth;
    const float bb = -ts * sth;
    const float d  =  ts * sth;
    const float e  =  ts * cth;

    const float xs = ((float)col + 0.5f) * (2.0f / (float)W_) - 1.0f;
    const float ys = ((float)row + 0.5f) * (2.0f / (float)H_) - 1.0f;

    const float gx = a * xs + bb * ys + tx;
    const float gy = d * xs + e  * ys + ty;

    float ix = ((gx + 1.0f) * (float)W_ - 1.0f) * 0.5f;
    float iy = ((gy + 1.0f) * (float)H_ - 1.0f) * 0.5f;
    ix = reflect_coord(ix, W_);
    iy = reflect_coord(iy, H_);

    const float ix0f = floorf(ix);
    const float iy0f = floorf(iy);
    const float fx = ix - ix0f;
    const float fy = iy - iy0f;

    const int x0 = min(max((int)ix0f,     0), W_ - 1);
    const int x1 = min(max((int)ix0f + 1, 0), W_ - 1);
    const int y0 = min(max((int)iy0f,     0), H_ - 1);
    const int y1 = min(max((int)iy0f + 1, 0), H_ - 1);

    const float w00 = (1.0f - fx) * (1.0f - fy);
    const float w01 = fx * (1.0f - fy);
    const float w10 = (1.0f - fx) * fy;
    const float w11 = fx * fy;

    const size_t plane = (size_t)H_ * W_;
    const float* img = x + (size_t)b * C_ * plane;
    float* o = out + (size_t)b * C_ * plane + (size_t)row * W_ + col;

    const size_t i00 = (size_t)y0 * W_ + x0;
    const size_t i01 = (size_t)y0 * W_ + x1;
    const size_t i10 = (size_t)y1 * W_ + x0;
    const size_t i11 = (size_t)y1 * W_ + x1;

    #pragma unroll
    for (int ch = 0; ch < C_; ++ch) {
        const float* im = img + (size_t)ch * plane;
        const float v00 = im[i00];
        const float v01 = im[i01];
        const float v10 = im[i10];
        const float v11 = im[i11];
        o[(size_t)ch * plane] = v00 * w00 + v01 * w01 + v10 * w10 + v11 * w11;
    }
}

extern "C" void kernel_launch(void* const* d_in, const int* in_sizes, int n_in,
                              void* d_out, int out_size, void* d_ws, size_t ws_size,
                              hipStream_t stream) {
    const float* x = (const float*)d_in[0];
    const float* p = (const float*)d_in[1];
    float* out = (float*)d_out;

    dim3 block(256, 1, 1);
    dim3 grid(W_ / 256, H_, B_);
    st_kernel<<<grid, block, 0, stream>>>(x, p, out);
}